// Round 17
// baseline (44.957 us; speedup 1.0000x reference)
//
#include <hip/hip_runtime.h>
#include <stdint.h>

#define INPUT_SCALE 0.0078125f   // 2^-7

__device__ __forceinline__ uint32_t sadu8(uint32_t a, uint32_t b, uint32_t c) {
#if __has_builtin(__builtin_amdgcn_sad_u8)
    return __builtin_amdgcn_sad_u8(a, b, c);
#else
    uint32_t d;
    asm("v_sad_u8 %0, %1, %2, %3" : "=v"(d) : "v"(a), "v"(b), "v"(c));
    return d;
#endif
}

__device__ __forceinline__ uint32_t qbyte(float x) {
    // round(clip(x*128, -127, 127)) + 128  (rintf = round-half-even, matches jnp.round)
    float v = fminf(fmaxf(x * 128.0f, -127.0f), 127.0f);
    return (uint32_t)((int)rintf(v) + 128);
}

// ---------------- Kernel A: weight scale + pack, 9 blocks ----------------
// Tap-major: u = (t*32 + f)*8 + cg, t = kh*3+kw; one tap = 1 KB contiguous.
__global__ __launch_bounds__(256) void quant_weight(const float* __restrict__ w,
                                                    uint32_t* __restrict__ qwp) {
    __shared__ float red[256];
    __shared__ float s_inv;
    int tid = threadIdx.x;
    float m = 0.0f;
    for (int i = tid; i < 9216; i += 256) m = fmaxf(m, fabsf(w[i]));
    red[tid] = m;
    __syncthreads();
    for (int s = 128; s > 0; s >>= 1) {
        if (tid < s) red[tid] = fmaxf(red[tid], red[tid + s]);
        __syncthreads();
    }
    if (tid == 0) {
        float s = fmaxf(red[0] / 127.0f, 1e-8f);
        int e; float fr = frexpf(s, &e);            // s = fr * 2^e, fr in [0.5,1)
        int k = (fr >= 0.70710678118654752f) ? e : e - 1;  // round(log2(s))
        s_inv = exp2f((float)(-k));                 // 1/s_w, exact power of 2
    }
    __syncthreads();
    float inv = s_inv;
    int u = blockIdx.x * 256 + tid;                 // 9*256 = 2304 exactly
    {
        int t = u >> 8;            // tap 0..8
        int rem = u & 255;
        int f = rem >> 3, cg = rem & 7;
        int kh = t / 3, kw = t - kh * 3;
        uint32_t pk = 0;
        #pragma unroll
        for (int b = 0; b < 4; ++b) {
            int c = cg * 4 + b;
            float v = w[((f * 32 + c) * 3 + kh) * 3 + kw] * inv;
            v = fminf(fmaxf(v, -127.0f), 127.0f);
            pk |= ((uint32_t)((int)rintf(v) + 128) & 0xFFu) << (8 * b);
        }
        qwp[u] = pk;
    }
}

// ---------------- Kernel B: fused quantize + SAD conv ----------------
// Tile 16x16. 256 threads = 4 waves; wave = one 8-filter group; thread owns
// 4 px (rows r0, r0+4, r0+8, r0+12 of col c) x 8 filters -> acc[4][8].
// WHY (R15/R16 post-mortem): duty was pinned at 256 busy cy per ~300 cy
// drain (45%). Here: 1024 busy cy per wait (4 px) AND all inner-loop loads
// are ds_read_b128 (weights staged to LDS) -> IN-ORDER lgkm, compiler emits
// counted lgkmcnt(N) waits instead of the lgkmcnt(0) drains that OOO SMEM
// forces. Weight reads wave-uniform -> LDS broadcast, conflict-free.
// DS duty ~288 pipe-cy/tap vs 1024 VALU cy -> DS pipe 28%, overlappable.
#define LSTRIDE 12  // u32 per pixel slot (32B data + 16B pad)
__global__ __launch_bounds__(256, 4) void adder_conv_fused(const float* __restrict__ x,
                                                           const uint32_t* __restrict__ qwp,
                                                           float* __restrict__ out) {
    __shared__ __align__(16) uint32_t sx[18 * 18 * LSTRIDE];  // 15552 B
    __shared__ __align__(16) uint32_t swl[2304];              // 9216 B (tap-major weights)
    int tid = threadIdx.x;
    // XCD-contiguous remap: XCD k owns 128 consecutive tiles (2 images).
    int b = ((blockIdx.x & 7) << 7) + (blockIdx.x >> 3);
    int n = b >> 6;                 // image 0..15
    int rem = b & 63;               // tile in image (8 rows x 8 cols of 16x16)
    int h0 = (rem >> 3) * 16, w0 = (rem & 7) * 16;

    // stage weights (uint4 granularity: 576 uint4)
    for (int i = tid; i < 576; i += 256)
        ((uint4*)swl)[i] = ((const uint4*)qwp)[i];

    // quantize + pack the 18x18 halo (32 ch -> 8 u32/pixel) into LDS.
    // cg = q/324: lanes sweep consecutive pixels of one channel-group.
    for (int q = tid; q < 2592; q += 256) {          // 2592 = 324 px * 8 cg
        int cg = q / 324;
        int pixel = q - cg * 324;
        int r = pixel / 18, cc = pixel - r * 18;
        int gh = h0 - 1 + r, gw = w0 - 1 + cc;
        uint32_t pk = 0x80808080u;                   // quantized-zero padding
        if ((unsigned)gh < 128u && (unsigned)gw < 128u) {
            const float* base = x + (((size_t)n * 32 + cg * 4) * 128 + gh) * 128 + gw;
            pk = qbyte(base[0])
               | (qbyte(base[16384]) << 8)
               | (qbyte(base[32768]) << 16)
               | (qbyte(base[49152]) << 24);
        }
        sx[pixel * LSTRIDE + cg] = pk;
    }
    __syncthreads();

    int fg = __builtin_amdgcn_readfirstlane(tid >> 6);  // filter group (wave-uniform)
    int lane = tid & 63;
    int c  = lane & 15;       // col in tile 0..15
    int r0 = lane >> 4;       // row base 0..3 -> rows r0, r0+4, r0+8, r0+12

    uint32_t acc[4][8];
    #pragma unroll
    for (int j = 0; j < 4; ++j)
        #pragma unroll
        for (int f = 0; f < 8; ++f) acc[j][f] = 0u;

    #pragma unroll 1
    for (int t = 0; t < 9; ++t) {
        int kh = t / 3, kw = t - kh * 3;
        // 4 pixel neighborhoods for this tap (8 ds_read_b128, tap-transient)
        uint4 px[4][2];
        #pragma unroll
        for (int j = 0; j < 4; ++j) {
            const uint4* p = (const uint4*)(sx + ((r0 + 4 * j + kh) * 18 + (c + kw)) * LSTRIDE);
            px[j][0] = p[0];
            px[j][1] = p[1];
        }
        const uint32_t* wt = swl + (t * 32 + fg * 8) * 8;   // wave-uniform -> broadcast
        #pragma unroll
        for (int f = 0; f < 8; ++f) {
            const uint4* wp = (const uint4*)(wt + f * 8);
            uint4 wv0 = wp[0], wv1 = wp[1];
            #pragma unroll
            for (int j = 0; j < 4; ++j) {
                uint32_t a = acc[j][f];
                a = sadu8(px[j][0].x, wv0.x, a);
                a = sadu8(px[j][0].y, wv0.y, a);
                a = sadu8(px[j][0].z, wv0.z, a);
                a = sadu8(px[j][0].w, wv0.w, a);
                a = sadu8(px[j][1].x, wv1.x, a);
                a = sadu8(px[j][1].y, wv1.y, a);
                a = sadu8(px[j][1].z, wv1.z, a);
                a = sadu8(px[j][1].w, wv1.w, a);
                acc[j][f] = a;
            }
        }
    }

    #pragma unroll
    for (int f = 0; f < 8; ++f) {
        size_t obase = ((size_t)(n * 32 + fg * 8 + f) * 16384) + (size_t)h0 * 128 + (w0 + c);
        #pragma unroll
        for (int j = 0; j < 4; ++j) {
            out[obase + (size_t)(r0 + 4 * j) * 128] = -(float)acc[j][f] * INPUT_SCALE;
        }
    }
}

extern "C" void kernel_launch(void* const* d_in, const int* in_sizes, int n_in,
                              void* d_out, int out_size, void* d_ws, size_t ws_size,
                              hipStream_t stream) {
    const float* x = (const float*)d_in[0];       // (16,32,128,128)
    const float* w = (const float*)d_in[1];       // (32,32,3,3)
    float* out = (float*)d_out;                   // (16,32,128,128)

    uint32_t* qwp = (uint32_t*)d_ws;              // 9216 B

    quant_weight<<<9, 256, 0, stream>>>(w, qwp);
    adder_conv_fused<<<1024, 256, 0, stream>>>(x, qwp, out);
}